// Round 1
// baseline (2040.483 us; speedup 1.0000x reference)
//
#include <hip/hip_runtime.h>

#define NN 100000
#define NCELL 40000
#define NDRUG 60000
#define EE 1600000
#define FEPS 1e-5f
#define SLOPE 0.2f

// ---------------------------------------------------------------- CSR build
__global__ __launch_bounds__(256) void edge_count_k(const int* __restrict__ dst,
                                                    int* __restrict__ deg, int E) {
  int e = blockIdx.x * 256 + threadIdx.x;
  if (e < E) atomicAdd(&deg[dst[e]], 1);
}

__global__ __launch_bounds__(1024) void scan_deg_k(const int* __restrict__ deg,
                                                   int* __restrict__ rowp,
                                                   float* __restrict__ dis,
                                                   int n, int E) {
  __shared__ int part[1024];
  const int t = threadIdx.x;
  const int chunk = (n + 1023) >> 10;
  const int lo = min(t * chunk, n);
  const int hi = min(lo + chunk, n);
  int s = 0;
  for (int i = lo; i < hi; i++) s += deg[i];
  part[t] = s;
  __syncthreads();
  for (int off = 1; off < 1024; off <<= 1) {
    int v = part[t];
    int u = (t >= off) ? part[t - off] : 0;
    __syncthreads();
    part[t] = v + u;
    __syncthreads();
  }
  int run = (t == 0) ? 0 : part[t - 1];
  for (int i = lo; i < hi; i++) {
    int d = deg[i];
    rowp[i] = run;
    run += d;
    dis[i] = (d > 0) ? rsqrtf((float)d) : 0.f;
  }
  if (t == 0) rowp[n] = E;
}

__global__ __launch_bounds__(256) void edge_fill_k(const int* __restrict__ src,
                                                   const int* __restrict__ dst,
                                                   const int* __restrict__ rowp,
                                                   int* __restrict__ cur,
                                                   int* __restrict__ esrc, int E) {
  int e = blockIdx.x * 256 + threadIdx.x;
  if (e >= E) return;
  int d = dst[e];
  int p = atomicAdd(&cur[d], 1);
  esrc[rowp[d] + p] = src[e];
}

// ---------------------------------------------------------------- GEMM
// Y[nrows,128] (+)= X[nrows,128] @ W[128,128]; optional bias, accumulate, act.
// act: 0 none, 1 leaky_relu(0.2), 2 relu
__global__ __launch_bounds__(256) void gemm128_k(const float* __restrict__ X,
                                                 const float* __restrict__ W,
                                                 const float* __restrict__ bias,
                                                 float* __restrict__ Y,
                                                 int nrows, int accflag, int act) {
  __shared__ float sX[32][68];   // [kk][row], padded
  __shared__ float sW[32][132];  // [kk][col], padded
  const int t = threadIdx.x;
  const int block_row = blockIdx.x * 64;
  const int cg = t & 31;   // col group -> cols cg*4..cg*4+3
  const int rg = t >> 5;   // row group -> rows rg*8..rg*8+7

  float acc[8][4];
#pragma unroll
  for (int i = 0; i < 8; i++)
#pragma unroll
    for (int j = 0; j < 4; j++) acc[i][j] = 0.f;

  const int lr = t >> 2;          // 0..63 tile row for X load
  const int lk = (t & 3) * 8;     // k offset for X load
  int grow = block_row + lr;
  if (grow >= nrows) grow = nrows - 1;
  const float* Xr = X + (size_t)grow * 128;

  const int wc4 = (t & 31) * 4;   // col for W load
  const int wk = t >> 5;          // 0..7

  for (int k0 = 0; k0 < 128; k0 += 32) {
    __syncthreads();
    float4 a0 = *(const float4*)(Xr + k0 + lk);
    float4 a1 = *(const float4*)(Xr + k0 + lk + 4);
    sX[lk + 0][lr] = a0.x; sX[lk + 1][lr] = a0.y;
    sX[lk + 2][lr] = a0.z; sX[lk + 3][lr] = a0.w;
    sX[lk + 4][lr] = a1.x; sX[lk + 5][lr] = a1.y;
    sX[lk + 6][lr] = a1.z; sX[lk + 7][lr] = a1.w;
#pragma unroll
    for (int q = 0; q < 4; q++) {
      int kk = wk + q * 8;
      *(float4*)&sW[kk][wc4] = *(const float4*)(W + (size_t)(k0 + kk) * 128 + wc4);
    }
    __syncthreads();
#pragma unroll
    for (int kk = 0; kk < 32; kk++) {
      float xa[8];
      *(float4*)&xa[0] = *(const float4*)&sX[kk][rg * 8];
      *(float4*)&xa[4] = *(const float4*)&sX[kk][rg * 8 + 4];
      float wb[4];
      *(float4*)&wb[0] = *(const float4*)&sW[kk][cg * 4];
#pragma unroll
      for (int i = 0; i < 8; i++)
#pragma unroll
        for (int j = 0; j < 4; j++) acc[i][j] += xa[i] * wb[j];
    }
  }

  float bv[4] = {0.f, 0.f, 0.f, 0.f};
  if (bias) {
    bv[0] = bias[cg * 4 + 0]; bv[1] = bias[cg * 4 + 1];
    bv[2] = bias[cg * 4 + 2]; bv[3] = bias[cg * 4 + 3];
  }
#pragma unroll
  for (int i = 0; i < 8; i++) {
    int r = block_row + rg * 8 + i;
    if (r < nrows) {
      float* yp = Y + (size_t)r * 128 + cg * 4;
      float o[4];
#pragma unroll
      for (int j = 0; j < 4; j++) o[j] = acc[i][j] + bv[j];
      if (accflag) {
        float4 old = *(const float4*)yp;
        o[0] += old.x; o[1] += old.y; o[2] += old.z; o[3] += old.w;
      }
      if (act == 1) {
#pragma unroll
        for (int j = 0; j < 4; j++) o[j] = o[j] > 0.f ? o[j] : SLOPE * o[j];
      } else if (act == 2) {
#pragma unroll
        for (int j = 0; j < 4; j++) o[j] = o[j] > 0.f ? o[j] : 0.f;
      }
      *(float4*)yp = make_float4(o[0], o[1], o[2], o[3]);
    }
  }
}

// ---------------------------------------------------------------- gather
// out[r,:] = leaky_relu( sum_{e: dst=r} dis[src]*dis[r] * xw[src,:] + bias )
__global__ __launch_bounds__(256) void gcn_gather_k(const float* __restrict__ xw,
                                                    const int* __restrict__ rowp,
                                                    const int* __restrict__ esrc,
                                                    const float* __restrict__ dis,
                                                    const float* __restrict__ bias,
                                                    float* __restrict__ out, int nrows) {
  const int lane = threadIdx.x & 63;
  const int row = (blockIdx.x * blockDim.x + threadIdx.x) >> 6;
  if (row >= nrows) return;
  const int start = rowp[row];
  const int end = rowp[row + 1];
  const float dr = dis[row];
  const int c0 = lane * 2;
  float ax = 0.f, ay = 0.f;
  for (int j0 = start; j0 < end; j0 += 64) {
    const int cnt = min(64, end - j0);
    int s = 0;
    float w = 0.f;
    if (lane < cnt) {
      s = esrc[j0 + lane];
      w = dis[s];
    }
    for (int j = 0; j < cnt; j++) {
      const int sj = __shfl(s, j, 64);
      const float wj = __shfl(w, j, 64) * dr;
      const float2 v = *(const float2*)(xw + (size_t)sj * 128 + c0);
      ax += wj * v.x;
      ay += wj * v.y;
    }
  }
  float ox = ax + bias[c0];
  float oy = ay + bias[c0 + 1];
  ox = ox > 0.f ? ox : SLOPE * ox;
  oy = oy > 0.f ? oy : SLOPE * oy;
  *(float2*)(out + (size_t)row * 128 + c0) = make_float2(ox, oy);
}

// ---------------------------------------------------------------- batchnorm
__global__ __launch_bounds__(256) void bn_stats_k(const float* __restrict__ X,
                                                  float* __restrict__ sums,
                                                  float* __restrict__ sumsq, int nrows) {
  __shared__ float ls[256], lq[256];
  const int t = threadIdx.x;
  const int c = t & 127;
  const int h = t >> 7;
  const int r0 = blockIdx.x * 256;
  const int r1 = min(r0 + 256, nrows);
  float s = 0.f, q = 0.f;
  for (int r = r0 + h; r < r1; r += 2) {
    float v = X[(size_t)r * 128 + c];
    s += v;
    q += v * v;
  }
  ls[t] = s;
  lq[t] = q;
  __syncthreads();
  if (t < 128) {
    s = ls[t] + ls[t + 128];
    q = lq[t] + lq[t + 128];
    atomicAdd(&sums[c], s);
    atomicAdd(&sumsq[c], q);
  }
}

__global__ void bn_finalize_k(const float* __restrict__ sums,
                              const float* __restrict__ sumsq,
                              const float* __restrict__ g,
                              const float* __restrict__ be,
                              float* __restrict__ scl, float* __restrict__ sht) {
  int c = threadIdx.x;
  float mu = sums[c] * (1.f / (float)NN);
  float var = sumsq[c] * (1.f / (float)NN) - mu * mu;
  float s = g[c] * rsqrtf(var + FEPS);
  scl[c] = s;
  sht[c] = be[c] - mu * s;
}

__global__ __launch_bounds__(256) void bn_apply_k(const float* __restrict__ X,
                                                  const float* __restrict__ scl,
                                                  const float* __restrict__ sht,
                                                  float* __restrict__ Y, int n4) {
  int idx = blockIdx.x * 256 + threadIdx.x;
  if (idx >= n4) return;
  int c4 = idx & 31;
  float4 x = ((const float4*)X)[idx];
  float4 s = ((const float4*)scl)[c4];
  float4 t4 = ((const float4*)sht)[c4];
  float4 y;
  y.x = x.x * s.x + t4.x;
  y.y = x.y * s.y + t4.y;
  y.z = x.z * s.z + t4.z;
  y.w = x.w * s.w + t4.w;
  ((float4*)Y)[idx] = y;
}

// ---------------------------------------------------------------- launch
extern "C" void kernel_launch(void* const* d_in, const int* in_sizes, int n_in,
                              void* d_out, int out_size, void* d_ws, size_t ws_size,
                              hipStream_t stream) {
  const float* feature = (const float*)d_in[0];
  const int* sen_edge = (const int*)d_in[1];
  const int* res_edge = (const int*)d_in[2];
  const float* W_sen1 = (const float*)d_in[3];
  const float* b_sen1 = (const float*)d_in[4];
  const float* W_sen2 = (const float*)d_in[5];
  const float* b_sen2 = (const float*)d_in[6];
  const float* W_senfc = (const float*)d_in[7];
  const float* b_senfc = (const float*)d_in[8];
  const float* g_sen = (const float*)d_in[9];
  const float* be_sen = (const float*)d_in[10];
  const float* W_res1 = (const float*)d_in[11];
  const float* b_res1 = (const float*)d_in[12];
  const float* W_res2 = (const float*)d_in[13];
  const float* b_res2 = (const float*)d_in[14];
  const float* W_resfc = (const float*)d_in[15];
  const float* b_resfc = (const float*)d_in[16];
  const float* g_res = (const float*)d_in[17];
  const float* be_res = (const float*)d_in[18];
  const float* W_cell = (const float*)d_in[19];
  const float* b_cell = (const float*)d_in[20];
  const float* W_drug = (const float*)d_in[21];
  const float* b_drug = (const float*)d_in[22];
  float* out = (float*)d_out;

  const size_t NF = (size_t)NN * 128;
  float* ws = (float*)d_ws;
  float* x1 = ws;
  float* x2 = ws + NF;
  float* xw = ws + 2 * NF;
  float* bnS = ws + 3 * NF;
  float* bnR = ws + 4 * NF;
  float* dis = ws + 5 * NF;                 // NN floats
  int* rowp = (int*)(dis + NN);             // NN+1 ints
  int* cur = rowp + (NN + 1);               // NN ints
  int* esrc = cur + NN;                     // EE ints
  float* sums = (float*)(esrc + EE);        // 128
  float* sumsq = sums + 128;                // 128
  float* scl = sumsq + 128;                 // 128
  float* sht = scl + 128;                   // 128

  const int GEMM_N = (NN + 63) / 64;        // 1563
  const int GATH_N = (NN * 64 + 255) / 256; // 25000
  const int EB = (EE + 255) / 256;          // 6250
  const int STAT_N = (NN + 255) / 256;      // 391
  const int APPLY_N = (int)(NF / 4 / 256);  // 12500

  struct Branch {
    const int* edge;
    const float* W1; const float* b1;
    const float* W2; const float* b2;
    const float* Wfc; const float* bfc;
    const float* g; const float* be;
    float* bn;
  };
  Branch br[2] = {
      {sen_edge, W_sen1, b_sen1, W_sen2, b_sen2, W_senfc, b_senfc, g_sen, be_sen, bnS},
      {res_edge, W_res1, b_res1, W_res2, b_res2, W_resfc, b_resfc, g_res, be_res, bnR},
  };

  for (int b = 0; b < 2; b++) {
    const int* src = br[b].edge;
    const int* dst = br[b].edge + EE;
    // CSR + norm
    hipMemsetAsync(cur, 0, NN * sizeof(int), stream);
    edge_count_k<<<EB, 256, 0, stream>>>(dst, cur, EE);
    scan_deg_k<<<1, 1024, 0, stream>>>(cur, rowp, dis, NN, EE);
    hipMemsetAsync(cur, 0, NN * sizeof(int), stream);
    edge_fill_k<<<EB, 256, 0, stream>>>(src, dst, rowp, cur, esrc, EE);
    // layer 1
    gemm128_k<<<GEMM_N, 256, 0, stream>>>(feature, br[b].W1, nullptr, xw, NN, 0, 0);
    gcn_gather_k<<<GATH_N, 256, 0, stream>>>(xw, rowp, esrc, dis, br[b].b1, x1, NN);
    // layer 2
    gemm128_k<<<GEMM_N, 256, 0, stream>>>(x1, br[b].W2, nullptr, xw, NN, 0, 0);
    gcn_gather_k<<<GATH_N, 256, 0, stream>>>(xw, rowp, esrc, dis, br[b].b2, x2, NN);
    // fc: concat([feature,x1,x2]) @ Wfc + bfc, relu
    gemm128_k<<<GEMM_N, 256, 0, stream>>>(feature, br[b].Wfc, br[b].bfc, xw, NN, 0, 0);
    gemm128_k<<<GEMM_N, 256, 0, stream>>>(x1, br[b].Wfc + 128 * 128, nullptr, xw, NN, 1, 0);
    gemm128_k<<<GEMM_N, 256, 0, stream>>>(x2, br[b].Wfc + 256 * 128, nullptr, xw, NN, 1, 2);
    // batchnorm
    hipMemsetAsync(sums, 0, 2 * 128 * sizeof(float), stream);
    bn_stats_k<<<STAT_N, 256, 0, stream>>>(xw, sums, sumsq, NN);
    bn_finalize_k<<<1, 128, 0, stream>>>(sums, sumsq, br[b].g, br[b].be, scl, sht);
    bn_apply_k<<<APPLY_N, 256, 0, stream>>>(xw, scl, sht, br[b].bn, (int)(NF / 4));
  }

  // heads
  const int GEMM_C = (NCELL + 63) / 64;
  const int GEMM_D = (NDRUG + 63) / 64;
  // x_cell = relu(concat(bnS[:40k], bnR[:40k]) @ W_cell + b_cell)
  gemm128_k<<<GEMM_C, 256, 0, stream>>>(bnS, W_cell, b_cell, out, NCELL, 0, 0);
  gemm128_k<<<GEMM_C, 256, 0, stream>>>(bnR, W_cell + 128 * 128, nullptr, out, NCELL, 1, 2);
  // x_drug = relu(concat(bnS[40k:], bnR[40k:]) @ W_drug + b_drug)
  float* outD = out + (size_t)NCELL * 128;
  gemm128_k<<<GEMM_D, 256, 0, stream>>>(bnS + (size_t)NCELL * 128, W_drug, b_drug, outD, NDRUG, 0, 0);
  gemm128_k<<<GEMM_D, 256, 0, stream>>>(bnR + (size_t)NCELL * 128, W_drug + 128 * 128, nullptr, outD, NDRUG, 1, 2);
}

// Round 2
// 1533.458 us; speedup vs baseline: 1.3306x; 1.3306x over previous
//
#include <hip/hip_runtime.h>

#define NN 100000
#define NCELL 40000
#define NDRUG 60000
#define EE 1600000
#define FEPS 1e-5f
#define SLOPE 0.2f
#define NB 391  // (NN+255)/256

// ---------------------------------------------------------------- CSR build
__global__ __launch_bounds__(256) void edge_count_k(const int* __restrict__ dst,
                                                    int* __restrict__ deg, int E) {
  int e = blockIdx.x * 256 + threadIdx.x;
  if (e < E) atomicAdd(&deg[dst[e]], 1);
}

// phase A: per-block sums of deg
__global__ __launch_bounds__(256) void scan_partial_k(const int* __restrict__ deg,
                                                      int* __restrict__ part, int n) {
  __shared__ int sm[256];
  const int t = threadIdx.x;
  const int i = blockIdx.x * 256 + t;
  sm[t] = (i < n) ? deg[i] : 0;
  __syncthreads();
  for (int off = 128; off > 0; off >>= 1) {
    if (t < off) sm[t] += sm[t + off];
    __syncthreads();
  }
  if (t == 0) part[blockIdx.x] = sm[0];
}

// phase B: exclusive scan of the NB partials (single small block)
__global__ __launch_bounds__(512) void scan_top_k(int* __restrict__ part, int nb,
                                                  int* __restrict__ rowp, int n, int E) {
  __shared__ int sm[512];
  const int t = threadIdx.x;
  int v = (t < nb) ? part[t] : 0;
  sm[t] = v;
  __syncthreads();
  for (int off = 1; off < 512; off <<= 1) {
    int u = (t >= off) ? sm[t - off] : 0;
    __syncthreads();
    sm[t] += u;
    __syncthreads();
  }
  if (t < nb) part[t] = (t == 0) ? 0 : sm[t - 1];
  if (t == 0) rowp[n] = E;
}

// phase C: per-block exclusive re-scan + add block offset; also write dis
__global__ __launch_bounds__(256) void scan_final_k(const int* __restrict__ deg,
                                                    const int* __restrict__ part,
                                                    int* __restrict__ rowp,
                                                    float* __restrict__ dis, int n) {
  __shared__ int sm[256];
  const int t = threadIdx.x;
  const int i = blockIdx.x * 256 + t;
  const int d = (i < n) ? deg[i] : 0;
  sm[t] = d;
  __syncthreads();
  for (int off = 1; off < 256; off <<= 1) {
    int u = (t >= off) ? sm[t - off] : 0;
    __syncthreads();
    sm[t] += u;
    __syncthreads();
  }
  if (i < n) {
    rowp[i] = part[blockIdx.x] + sm[t] - d;
    dis[i] = (d > 0) ? rsqrtf((float)d) : 0.f;
  }
}

__global__ __launch_bounds__(256) void edge_fill_k(const int* __restrict__ src,
                                                   const int* __restrict__ dst,
                                                   const int* __restrict__ rowp,
                                                   int* __restrict__ cur,
                                                   int* __restrict__ esrc, int E) {
  int e = blockIdx.x * 256 + threadIdx.x;
  if (e >= E) return;
  int d = dst[e];
  int p = atomicAdd(&cur[d], 1);
  esrc[rowp[d] + p] = src[e];
}

// ---------------------------------------------------------------- GEMM
// Y[nrows,128] = act( [X0|X1|X2][nrows, nseg*128] @ W[nseg*128,128] + bias )
// act: 0 none, 1 leaky_relu(0.2), 2 relu
__global__ __launch_bounds__(256) void gemm_multi_k(const float* __restrict__ X0,
                                                    const float* __restrict__ X1,
                                                    const float* __restrict__ X2,
                                                    const float* __restrict__ W,
                                                    const float* __restrict__ bias,
                                                    float* __restrict__ Y,
                                                    int nrows, int nseg, int act) {
  __shared__ float sX[32][68];   // [kk][row], padded
  __shared__ float sW[32][132];  // [kk][col], padded
  const int t = threadIdx.x;
  const int block_row = blockIdx.x * 64;
  const int cg = t & 31;   // cols cg*4..cg*4+3
  const int rg = t >> 5;   // rows rg*8..rg*8+7

  float acc[8][4];
#pragma unroll
  for (int i = 0; i < 8; i++)
#pragma unroll
    for (int j = 0; j < 4; j++) acc[i][j] = 0.f;

  const int lr = t >> 2;          // 0..63 tile row for X load
  const int lk = (t & 3) * 8;     // k offset for X load
  int grow = block_row + lr;
  if (grow >= nrows) grow = nrows - 1;
  const size_t xoff = (size_t)grow * 128;

  const int wc4 = (t & 31) * 4;   // col for W load
  const int wk = t >> 5;          // 0..7

  for (int seg = 0; seg < nseg; seg++) {
    const float* Xr = (seg == 0 ? X0 : (seg == 1 ? X1 : X2)) + xoff;
    const float* Ws = W + (size_t)seg * 128 * 128;
    for (int k0 = 0; k0 < 128; k0 += 32) {
      __syncthreads();
      float4 a0 = *(const float4*)(Xr + k0 + lk);
      float4 a1 = *(const float4*)(Xr + k0 + lk + 4);
      sX[lk + 0][lr] = a0.x; sX[lk + 1][lr] = a0.y;
      sX[lk + 2][lr] = a0.z; sX[lk + 3][lr] = a0.w;
      sX[lk + 4][lr] = a1.x; sX[lk + 5][lr] = a1.y;
      sX[lk + 6][lr] = a1.z; sX[lk + 7][lr] = a1.w;
#pragma unroll
      for (int q = 0; q < 4; q++) {
        int kk = wk + q * 8;
        *(float4*)&sW[kk][wc4] = *(const float4*)(Ws + (size_t)(k0 + kk) * 128 + wc4);
      }
      __syncthreads();
#pragma unroll
      for (int kk = 0; kk < 32; kk++) {
        float xa[8];
        *(float4*)&xa[0] = *(const float4*)&sX[kk][rg * 8];
        *(float4*)&xa[4] = *(const float4*)&sX[kk][rg * 8 + 4];
        float wb[4];
        *(float4*)&wb[0] = *(const float4*)&sW[kk][cg * 4];
#pragma unroll
        for (int i = 0; i < 8; i++)
#pragma unroll
          for (int j = 0; j < 4; j++) acc[i][j] += xa[i] * wb[j];
      }
    }
  }

  float bv[4] = {0.f, 0.f, 0.f, 0.f};
  if (bias) {
    bv[0] = bias[cg * 4 + 0]; bv[1] = bias[cg * 4 + 1];
    bv[2] = bias[cg * 4 + 2]; bv[3] = bias[cg * 4 + 3];
  }
#pragma unroll
  for (int i = 0; i < 8; i++) {
    int r = block_row + rg * 8 + i;
    if (r < nrows) {
      float* yp = Y + (size_t)r * 128 + cg * 4;
      float o[4];
#pragma unroll
      for (int j = 0; j < 4; j++) o[j] = acc[i][j] + bv[j];
      if (act == 1) {
#pragma unroll
        for (int j = 0; j < 4; j++) o[j] = o[j] > 0.f ? o[j] : SLOPE * o[j];
      } else if (act == 2) {
#pragma unroll
        for (int j = 0; j < 4; j++) o[j] = o[j] > 0.f ? o[j] : 0.f;
      }
      *(float4*)yp = make_float4(o[0], o[1], o[2], o[3]);
    }
  }
}

// ---------------------------------------------------------------- gather
// out[r,:] = leaky_relu( sum_{e: dst=r} dis[src]*dis[r] * xw[src,:] + bias )
__global__ __launch_bounds__(256) void gcn_gather_k(const float* __restrict__ xw,
                                                    const int* __restrict__ rowp,
                                                    const int* __restrict__ esrc,
                                                    const float* __restrict__ dis,
                                                    const float* __restrict__ bias,
                                                    float* __restrict__ out, int nrows) {
  const int lane = threadIdx.x & 63;
  const int row = (blockIdx.x * blockDim.x + threadIdx.x) >> 6;
  if (row >= nrows) return;
  const int start = rowp[row];
  const int end = rowp[row + 1];
  const float dr = dis[row];
  const int c0 = lane * 2;
  float ax = 0.f, ay = 0.f;
  for (int j0 = start; j0 < end; j0 += 64) {
    const int cnt = min(64, end - j0);
    int s = 0;
    float w = 0.f;
    if (lane < cnt) {
      s = esrc[j0 + lane];
      w = dis[s];
    }
    for (int j = 0; j < cnt; j++) {
      const int sj = __shfl(s, j, 64);
      const float wj = __shfl(w, j, 64) * dr;
      const float2 v = *(const float2*)(xw + (size_t)sj * 128 + c0);
      ax += wj * v.x;
      ay += wj * v.y;
    }
  }
  float ox = ax + bias[c0];
  float oy = ay + bias[c0 + 1];
  ox = ox > 0.f ? ox : SLOPE * ox;
  oy = oy > 0.f ? oy : SLOPE * oy;
  *(float2*)(out + (size_t)row * 128 + c0) = make_float2(ox, oy);
}

// ---------------------------------------------------------------- batchnorm
__global__ __launch_bounds__(256) void bn_stats_k(const float* __restrict__ X,
                                                  float* __restrict__ sums,
                                                  float* __restrict__ sumsq, int nrows) {
  __shared__ float ls[256], lq[256];
  const int t = threadIdx.x;
  const int c = t & 127;
  const int h = t >> 7;
  const int r0 = blockIdx.x * 256;
  const int r1 = min(r0 + 256, nrows);
  float s = 0.f, q = 0.f;
  for (int r = r0 + h; r < r1; r += 2) {
    float v = X[(size_t)r * 128 + c];
    s += v;
    q += v * v;
  }
  ls[t] = s;
  lq[t] = q;
  __syncthreads();
  if (t < 128) {
    s = ls[t] + ls[t + 128];
    q = lq[t] + lq[t + 128];
    atomicAdd(&sums[c], s);
    atomicAdd(&sumsq[c], q);
  }
}

__global__ void bn_finalize_k(const float* __restrict__ sums,
                              const float* __restrict__ sumsq,
                              const float* __restrict__ g,
                              const float* __restrict__ be,
                              float* __restrict__ scl, float* __restrict__ sht) {
  int c = threadIdx.x;
  float mu = sums[c] * (1.f / (float)NN);
  float var = sumsq[c] * (1.f / (float)NN) - mu * mu;
  float s = g[c] * rsqrtf(var + FEPS);
  scl[c] = s;
  sht[c] = be[c] - mu * s;
}

__global__ __launch_bounds__(256) void bn_apply_k(const float* __restrict__ X,
                                                  const float* __restrict__ scl,
                                                  const float* __restrict__ sht,
                                                  float* __restrict__ Y, int n4) {
  int idx = blockIdx.x * 256 + threadIdx.x;
  if (idx >= n4) return;
  int c4 = idx & 31;
  float4 x = ((const float4*)X)[idx];
  float4 s = ((const float4*)scl)[c4];
  float4 t4 = ((const float4*)sht)[c4];
  float4 y;
  y.x = x.x * s.x + t4.x;
  y.y = x.y * s.y + t4.y;
  y.z = x.z * s.z + t4.z;
  y.w = x.w * s.w + t4.w;
  ((float4*)Y)[idx] = y;
}

// ---------------------------------------------------------------- launch
extern "C" void kernel_launch(void* const* d_in, const int* in_sizes, int n_in,
                              void* d_out, int out_size, void* d_ws, size_t ws_size,
                              hipStream_t stream) {
  const float* feature = (const float*)d_in[0];
  const int* sen_edge = (const int*)d_in[1];
  const int* res_edge = (const int*)d_in[2];
  const float* W_sen1 = (const float*)d_in[3];
  const float* b_sen1 = (const float*)d_in[4];
  const float* W_sen2 = (const float*)d_in[5];
  const float* b_sen2 = (const float*)d_in[6];
  const float* W_senfc = (const float*)d_in[7];
  const float* b_senfc = (const float*)d_in[8];
  const float* g_sen = (const float*)d_in[9];
  const float* be_sen = (const float*)d_in[10];
  const float* W_res1 = (const float*)d_in[11];
  const float* b_res1 = (const float*)d_in[12];
  const float* W_res2 = (const float*)d_in[13];
  const float* b_res2 = (const float*)d_in[14];
  const float* W_resfc = (const float*)d_in[15];
  const float* b_resfc = (const float*)d_in[16];
  const float* g_res = (const float*)d_in[17];
  const float* be_res = (const float*)d_in[18];
  const float* W_cell = (const float*)d_in[19];
  const float* b_cell = (const float*)d_in[20];
  const float* W_drug = (const float*)d_in[21];
  const float* b_drug = (const float*)d_in[22];
  float* out = (float*)d_out;

  const size_t NF = (size_t)NN * 128;
  float* ws = (float*)d_ws;
  float* x1 = ws;
  float* x2 = ws + NF;
  float* xw = ws + 2 * NF;
  float* bnS = ws + 3 * NF;
  float* bnR = ws + 4 * NF;
  float* dis = ws + 5 * NF;                 // NN floats
  int* rowp = (int*)(dis + NN);             // NN+1 ints
  int* cur = rowp + (NN + 1);               // NN ints
  int* esrc = cur + NN;                     // EE ints
  float* sums = (float*)(esrc + EE);        // 128
  float* sumsq = sums + 128;                // 128
  float* scl = sumsq + 128;                 // 128
  float* sht = scl + 128;                   // 128
  int* part = (int*)(sht + 128);            // NB ints

  const int GEMM_N = (NN + 63) / 64;        // 1563
  const int GATH_N = (NN * 64 + 255) / 256; // 25000
  const int EB = (EE + 255) / 256;          // 6250
  const int STAT_N = (NN + 255) / 256;      // 391
  const int APPLY_N = (int)(NF / 4 / 256);  // 12500

  struct Branch {
    const int* edge;
    const float* W1; const float* b1;
    const float* W2; const float* b2;
    const float* Wfc; const float* bfc;
    const float* g; const float* be;
    float* bn;
  };
  Branch br[2] = {
      {sen_edge, W_sen1, b_sen1, W_sen2, b_sen2, W_senfc, b_senfc, g_sen, be_sen, bnS},
      {res_edge, W_res1, b_res1, W_res2, b_res2, W_resfc, b_resfc, g_res, be_res, bnR},
  };

  for (int b = 0; b < 2; b++) {
    const int* src = br[b].edge;
    const int* dst = br[b].edge + EE;
    // CSR + norm (parallel 3-phase scan)
    hipMemsetAsync(cur, 0, NN * sizeof(int), stream);
    edge_count_k<<<EB, 256, 0, stream>>>(dst, cur, EE);
    scan_partial_k<<<NB, 256, 0, stream>>>(cur, part, NN);
    scan_top_k<<<1, 512, 0, stream>>>(part, NB, rowp, NN, EE);
    scan_final_k<<<NB, 256, 0, stream>>>(cur, part, rowp, dis, NN);
    hipMemsetAsync(cur, 0, NN * sizeof(int), stream);
    edge_fill_k<<<EB, 256, 0, stream>>>(src, dst, rowp, cur, esrc, EE);
    // layer 1
    gemm_multi_k<<<GEMM_N, 256, 0, stream>>>(feature, nullptr, nullptr, br[b].W1, nullptr, xw, NN, 1, 0);
    gcn_gather_k<<<GATH_N, 256, 0, stream>>>(xw, rowp, esrc, dis, br[b].b1, x1, NN);
    // layer 2
    gemm_multi_k<<<GEMM_N, 256, 0, stream>>>(x1, nullptr, nullptr, br[b].W2, nullptr, xw, NN, 1, 0);
    gcn_gather_k<<<GATH_N, 256, 0, stream>>>(xw, rowp, esrc, dis, br[b].b2, x2, NN);
    // fc: concat([feature,x1,x2]) @ Wfc + bfc, relu  (single K=384 GEMM)
    gemm_multi_k<<<GEMM_N, 256, 0, stream>>>(feature, x1, x2, br[b].Wfc, br[b].bfc, xw, NN, 3, 2);
    // batchnorm
    hipMemsetAsync(sums, 0, 2 * 128 * sizeof(float), stream);
    bn_stats_k<<<STAT_N, 256, 0, stream>>>(xw, sums, sumsq, NN);
    bn_finalize_k<<<1, 128, 0, stream>>>(sums, sumsq, br[b].g, br[b].be, scl, sht);
    bn_apply_k<<<APPLY_N, 256, 0, stream>>>(xw, scl, sht, br[b].bn, (int)(NF / 4));
  }

  // heads (single K=256 GEMM each)
  const int GEMM_C = (NCELL + 63) / 64;
  const int GEMM_D = (NDRUG + 63) / 64;
  gemm_multi_k<<<GEMM_C, 256, 0, stream>>>(bnS, bnR, nullptr, W_cell, b_cell, out, NCELL, 2, 2);
  float* outD = out + (size_t)NCELL * 128;
  gemm_multi_k<<<GEMM_D, 256, 0, stream>>>(bnS + (size_t)NCELL * 128, bnR + (size_t)NCELL * 128, nullptr,
                                           W_drug, b_drug, outD, NDRUG, 2, 2);
}

// Round 5
// 1308.967 us; speedup vs baseline: 1.5588x; 1.1715x over previous
//
#include <hip/hip_runtime.h>

#define NN 100000
#define NCELL 40000
#define NDRUG 60000
#define EE 1600000
#define FEPS 1e-5f
#define SLOPE 0.2f
#define NB 391  // (NN+255)/256

typedef unsigned short ushort_t;
typedef unsigned int uint_t;
typedef __attribute__((ext_vector_type(8))) __bf16 bf16x8;
typedef __attribute__((ext_vector_type(4))) float f32x4;

__device__ __forceinline__ ushort_t f2bf(float x) {
  uint_t u = __float_as_uint(x);
  u = (u + 0x7FFFu + ((u >> 16) & 1u)) >> 16;  // RNE
  return (ushort_t)u;
}
__device__ __forceinline__ uint_t pack2bf(float a, float b) {
  return (uint_t)f2bf(a) | ((uint_t)f2bf(b) << 16);
}

// ---------------------------------------------------------------- converts
__global__ __launch_bounds__(256) void feat_cvt_k(const float* __restrict__ X,
                                                  ushort_t* __restrict__ Y, int n8) {
  int i = blockIdx.x * 256 + threadIdx.x;
  if (i >= n8) return;
  const float4* in4 = (const float4*)X;
  float4 a = in4[2 * i], b = in4[2 * i + 1];
  uint4 o;
  o.x = pack2bf(a.x, a.y); o.y = pack2bf(a.z, a.w);
  o.z = pack2bf(b.x, b.y); o.w = pack2bf(b.z, b.w);
  ((uint4*)Y)[i] = o;
}

struct WC { const float* s; ushort_t* d; int K; };
struct WCA { WC w[8]; };
// Wt[col][k] = bf16(W[k][col]); grid (8, maxK/16), block 128 (one col per thread)
__global__ __launch_bounds__(128) void wcvt_k(WCA a) {
  const WC wc = a.w[blockIdx.x];
  const int k0 = blockIdx.y * 16;
  if (k0 >= wc.K) return;
  const int col = threadIdx.x;
  const int k1 = min(k0 + 16, wc.K);
  for (int k = k0; k < k1; k++)
    wc.d[(size_t)col * wc.K + k] = f2bf(wc.s[(size_t)k * 128 + col]);
}

// ---------------------------------------------------------------- CSR build
__global__ __launch_bounds__(256) void edge_count_k(const int* __restrict__ dst,
                                                    int* __restrict__ deg, int E) {
  int e = blockIdx.x * 256 + threadIdx.x;
  if (e < E) atomicAdd(&deg[dst[e]], 1);
}

__global__ __launch_bounds__(256) void scan_partial_k(const int* __restrict__ deg,
                                                      int* __restrict__ part, int n) {
  __shared__ int sm[256];
  const int t = threadIdx.x;
  const int i = blockIdx.x * 256 + t;
  sm[t] = (i < n) ? deg[i] : 0;
  __syncthreads();
  for (int off = 128; off > 0; off >>= 1) {
    if (t < off) sm[t] += sm[t + off];
    __syncthreads();
  }
  if (t == 0) part[blockIdx.x] = sm[0];
}

__global__ __launch_bounds__(512) void scan_top_k(int* __restrict__ part, int nb,
                                                  int* __restrict__ rowp, int n, int E) {
  __shared__ int sm[512];
  const int t = threadIdx.x;
  int v = (t < nb) ? part[t] : 0;
  sm[t] = v;
  __syncthreads();
  for (int off = 1; off < 512; off <<= 1) {
    int u = (t >= off) ? sm[t - off] : 0;
    __syncthreads();
    sm[t] += u;
    __syncthreads();
  }
  if (t < nb) part[t] = (t == 0) ? 0 : sm[t - 1];
  if (t == 0) rowp[n] = E;
}

__global__ __launch_bounds__(256) void scan_final_k(const int* __restrict__ deg,
                                                    const int* __restrict__ part,
                                                    int* __restrict__ rowp,
                                                    float* __restrict__ dis, int n) {
  __shared__ int sm[256];
  const int t = threadIdx.x;
  const int i = blockIdx.x * 256 + t;
  const int d = (i < n) ? deg[i] : 0;
  sm[t] = d;
  __syncthreads();
  for (int off = 1; off < 256; off <<= 1) {
    int u = (t >= off) ? sm[t - off] : 0;
    __syncthreads();
    sm[t] += u;
    __syncthreads();
  }
  if (i < n) {
    rowp[i] = part[blockIdx.x] + sm[t] - d;
    dis[i] = (d > 0) ? rsqrtf((float)d) : 0.f;
  }
}

__global__ __launch_bounds__(256) void edge_fill_k(const int* __restrict__ src,
                                                   const int* __restrict__ dst,
                                                   const int* __restrict__ rowp,
                                                   int* __restrict__ cur,
                                                   int* __restrict__ esrc, int E) {
  int e = blockIdx.x * 256 + threadIdx.x;
  if (e >= E) return;
  int d = dst[e];
  int p = atomicAdd(&cur[d], 1);
  esrc[rowp[d] + p] = src[e];
}

// ---------------------------------------------------------------- MFMA GEMM
// Y[nrows,128] = act( [X0|X1|X2](bf16)[nrows, nseg*128] @ W[nseg*128,128] + bias )
// Wt is bf16 [128 cols][Ktot=nseg*128] (transposed). Output: Yf (fp32) or Yb (bf16).
// act: 0 none, 1 leaky, 2 relu. Block: 4 waves x 32 rows = 128 rows.
__global__ __launch_bounds__(256) void gemm_mfma_k(const ushort_t* __restrict__ X0,
                                                   const ushort_t* __restrict__ X1,
                                                   const ushort_t* __restrict__ X2,
                                                   const ushort_t* __restrict__ Wt,
                                                   const float* __restrict__ bias,
                                                   float* __restrict__ Yf,
                                                   ushort_t* __restrict__ Yb,
                                                   int nrows, int nseg, int act) {
  const int t = threadIdx.x;
  const int wave = t >> 6;
  const int lane = t & 63;
  const int lane15 = lane & 15;
  const int lgrp = lane >> 4;  // 0..3
  const int row0w = blockIdx.x * 128 + wave * 32;  // wave owns 32 rows
  const int Ktot = nseg * 128;

  // clamped A rows for the two 16-row subtiles
  const int r0c = min(row0w + lane15, nrows - 1);
  const int r1c = min(row0w + 16 + lane15, nrows - 1);

  f32x4 acc[2][8];
#pragma unroll
  for (int m = 0; m < 2; m++)
#pragma unroll
    for (int f = 0; f < 8; f++) acc[m][f] = (f32x4)0.f;

  const ushort_t* Xs[3] = {X0, X1, X2};
  for (int seg = 0; seg < nseg; seg++) {
    const ushort_t* Xp = Xs[seg];
    const ushort_t* Wp = Wt + seg * 128;
#pragma unroll
    for (int kk = 0; kk < 128; kk += 32) {
      const int ko = kk + lgrp * 8;
      bf16x8 a0 = *(const bf16x8*)(Xp + (size_t)r0c * 128 + ko);
      bf16x8 a1 = *(const bf16x8*)(Xp + (size_t)r1c * 128 + ko);
#pragma unroll
      for (int f = 0; f < 8; f++) {
        bf16x8 bb = *(const bf16x8*)(Wp + (size_t)(f * 16 + lane15) * Ktot + ko);
        acc[0][f] = __builtin_amdgcn_mfma_f32_16x16x32_bf16(a0, bb, acc[0][f], 0, 0, 0);
        acc[1][f] = __builtin_amdgcn_mfma_f32_16x16x32_bf16(a1, bb, acc[1][f], 0, 0, 0);
      }
    }
  }

#pragma unroll
  for (int m = 0; m < 2; m++) {
    const int rbase = row0w + m * 16 + lgrp * 4;
#pragma unroll
    for (int f = 0; f < 8; f++) {
      const int col = f * 16 + lane15;
      const float bv = bias ? bias[col] : 0.f;
#pragma unroll
      for (int j = 0; j < 4; j++) {
        const int r = rbase + j;
        if (r < nrows) {
          float o = acc[m][f][j] + bv;
          if (act == 1) o = o > 0.f ? o : SLOPE * o;
          else if (act == 2) o = o > 0.f ? o : 0.f;
          if (Yf) Yf[(size_t)r * 128 + col] = o;
          else Yb[(size_t)r * 128 + col] = f2bf(o);
        }
      }
    }
  }
}

// ---------------------------------------------------------------- gather (bf16)
// out[r,:] = bf16( leaky_relu( sum_{e: dst=r} dis[src]*dis[r] * xw[src,:] + bias ) )
__global__ __launch_bounds__(256) void gcn_gather_k(const ushort_t* __restrict__ xw,
                                                    const int* __restrict__ rowp,
                                                    const int* __restrict__ esrc,
                                                    const float* __restrict__ dis,
                                                    const float* __restrict__ bias,
                                                    ushort_t* __restrict__ out, int nrows) {
  const int lane = threadIdx.x & 63;
  const int row = (blockIdx.x * blockDim.x + threadIdx.x) >> 6;
  if (row >= nrows) return;
  const int start = rowp[row];
  const int end = rowp[row + 1];
  const float dr = dis[row];
  const int c0 = lane * 2;
  float ax = 0.f, ay = 0.f;
  for (int j0 = start; j0 < end; j0 += 64) {
    const int cnt = min(64, end - j0);
    int s = 0;
    float w = 0.f;
    if (lane < cnt) {
      s = esrc[j0 + lane];
      w = dis[s];
    }
    for (int j = 0; j < cnt; j++) {
      const int sj = __shfl(s, j, 64);
      const float wj = __shfl(w, j, 64) * dr;
      const uint_t v = *(const uint_t*)(xw + (size_t)sj * 128 + c0);
      const float f0 = __uint_as_float(v << 16);
      const float f1 = __uint_as_float(v & 0xFFFF0000u);
      ax += wj * f0;
      ay += wj * f1;
    }
  }
  float ox = ax + bias[c0];
  float oy = ay + bias[c0 + 1];
  ox = ox > 0.f ? ox : SLOPE * ox;
  oy = oy > 0.f ? oy : SLOPE * oy;
  ((uint_t*)out)[(size_t)row * 64 + lane] = pack2bf(ox, oy);
}

// ---------------------------------------------------------------- batchnorm
__global__ __launch_bounds__(256) void bn_stats_k(const float* __restrict__ X,
                                                  float* __restrict__ sums,
                                                  float* __restrict__ sumsq, int nrows) {
  __shared__ float ls[256], lq[256];
  const int t = threadIdx.x;
  const int c = t & 127;
  const int h = t >> 7;
  const int r0 = blockIdx.x * 256;
  const int r1 = min(r0 + 256, nrows);
  float s = 0.f, q = 0.f;
  for (int r = r0 + h; r < r1; r += 2) {
    float v = X[(size_t)r * 128 + c];
    s += v;
    q += v * v;
  }
  ls[t] = s;
  lq[t] = q;
  __syncthreads();
  if (t < 128) {
    s = ls[t] + ls[t + 128];
    q = lq[t] + lq[t + 128];
    atomicAdd(&sums[c], s);
    atomicAdd(&sumsq[c], q);
  }
}

__global__ void bn_finalize_k(const float* __restrict__ sums,
                              const float* __restrict__ sumsq,
                              const float* __restrict__ g,
                              const float* __restrict__ be,
                              float* __restrict__ scl, float* __restrict__ sht) {
  int c = threadIdx.x;
  float mu = sums[c] * (1.f / (float)NN);
  float var = sumsq[c] * (1.f / (float)NN) - mu * mu;
  float s = g[c] * rsqrtf(var + FEPS);
  scl[c] = s;
  sht[c] = be[c] - mu * s;
}

// reads fp32, writes bf16
__global__ __launch_bounds__(256) void bn_apply_k(const float* __restrict__ X,
                                                  const float* __restrict__ scl,
                                                  const float* __restrict__ sht,
                                                  ushort_t* __restrict__ Y, int n4) {
  int idx = blockIdx.x * 256 + threadIdx.x;
  if (idx >= n4) return;
  int c4 = idx & 31;
  float4 x = ((const float4*)X)[idx];
  float4 s = ((const float4*)scl)[c4];
  float4 t4 = ((const float4*)sht)[c4];
  uint2 o;
  o.x = pack2bf(x.x * s.x + t4.x, x.y * s.y + t4.y);
  o.y = pack2bf(x.z * s.z + t4.z, x.w * s.w + t4.w);
  ((uint2*)Y)[idx] = o;
}

// ---------------------------------------------------------------- launch
extern "C" void kernel_launch(void* const* d_in, const int* in_sizes, int n_in,
                              void* d_out, int out_size, void* d_ws, size_t ws_size,
                              hipStream_t stream) {
  const float* feature = (const float*)d_in[0];
  const int* sen_edge = (const int*)d_in[1];
  const int* res_edge = (const int*)d_in[2];
  const float* W_sen1 = (const float*)d_in[3];
  const float* b_sen1 = (const float*)d_in[4];
  const float* W_sen2 = (const float*)d_in[5];
  const float* b_sen2 = (const float*)d_in[6];
  const float* W_senfc = (const float*)d_in[7];
  const float* b_senfc = (const float*)d_in[8];
  const float* g_sen = (const float*)d_in[9];
  const float* be_sen = (const float*)d_in[10];
  const float* W_res1 = (const float*)d_in[11];
  const float* b_res1 = (const float*)d_in[12];
  const float* W_res2 = (const float*)d_in[13];
  const float* b_res2 = (const float*)d_in[14];
  const float* W_resfc = (const float*)d_in[15];
  const float* b_resfc = (const float*)d_in[16];
  const float* g_res = (const float*)d_in[17];
  const float* be_res = (const float*)d_in[18];
  const float* W_cell = (const float*)d_in[19];
  const float* b_cell = (const float*)d_in[20];
  const float* W_drug = (const float*)d_in[21];
  const float* b_drug = (const float*)d_in[22];
  float* out = (float*)d_out;

  const size_t NF = (size_t)NN * 128;
  char* wsb = (char*)d_ws;
  float* xw = (float*)wsb;                          // NF fp32
  ushort_t* featb = (ushort_t*)(wsb + NF * 4);      // NF bf16
  ushort_t* x1b = featb + NF;
  ushort_t* x2b = x1b + NF;
  ushort_t* xwb = x2b + NF;
  ushort_t* bnSb = xwb + NF;
  ushort_t* bnRb = bnSb + NF;
  ushort_t* wt = bnRb + NF;                         // weight pool
  ushort_t* W1tS = wt;                              // 128*128
  ushort_t* W2tS = W1tS + 128 * 128;
  ushort_t* WfctS = W2tS + 128 * 128;               // 128*384
  ushort_t* W1tR = WfctS + 128 * 384;
  ushort_t* W2tR = W1tR + 128 * 128;
  ushort_t* WfctR = W2tR + 128 * 128;
  ushort_t* Wcellt = WfctR + 128 * 384;             // 128*256
  ushort_t* Wdrugt = Wcellt + 128 * 256;
  float* dis = (float*)(Wdrugt + 128 * 256);        // NN
  int* rowp = (int*)(dis + NN);                     // NN+1
  int* cur = rowp + (NN + 1);                       // NN
  int* esrc = cur + NN;                             // EE
  float* sums = (float*)(esrc + EE);                // 128
  float* sumsq = sums + 128;
  float* scl = sumsq + 128;
  float* sht = scl + 128;
  int* part = (int*)(sht + 128);                    // NB

  const int MG = (NN + 127) / 128;          // 782 mfma-gemm blocks
  const int GATH_N = (NN * 64 + 255) / 256; // 25000
  const int EB = (EE + 255) / 256;          // 6250
  const int STAT_N = (NN + 255) / 256;      // 391
  const int APPLY_N = (int)(NF / 4 / 256);  // 12500

  // one-time converts
  feat_cvt_k<<<(int)(NF / 8 + 255) / 256, 256, 0, stream>>>(feature, featb, (int)(NF / 8));
  WCA wa;
  wa.w[0] = {W_sen1, W1tS, 128};  wa.w[1] = {W_sen2, W2tS, 128};
  wa.w[2] = {W_senfc, WfctS, 384}; wa.w[3] = {W_res1, W1tR, 128};
  wa.w[4] = {W_res2, W2tR, 128};  wa.w[5] = {W_resfc, WfctR, 384};
  wa.w[6] = {W_cell, Wcellt, 256}; wa.w[7] = {W_drug, Wdrugt, 256};
  wcvt_k<<<dim3(8, 24), 128, 0, stream>>>(wa);

  struct Branch {
    const int* edge;
    ushort_t* W1t; const float* b1;
    ushort_t* W2t; const float* b2;
    ushort_t* Wfct; const float* bfc;
    const float* g; const float* be;
    ushort_t* bnb;
  };
  Branch br[2] = {
      {sen_edge, W1tS, b_sen1, W2tS, b_sen2, WfctS, b_senfc, g_sen, be_sen, bnSb},
      {res_edge, W1tR, b_res1, W2tR, b_res2, WfctR, b_resfc, g_res, be_res, bnRb},
  };

  for (int b = 0; b < 2; b++) {
    const int* src = br[b].edge;
    const int* dst = br[b].edge + EE;
    (void)hipMemsetAsync(cur, 0, NN * sizeof(int), stream);
    edge_count_k<<<EB, 256, 0, stream>>>(dst, cur, EE);
    scan_partial_k<<<NB, 256, 0, stream>>>(cur, part, NN);
    scan_top_k<<<1, 512, 0, stream>>>(part, NB, rowp, NN, EE);
    scan_final_k<<<NB, 256, 0, stream>>>(cur, part, rowp, dis, NN);
    (void)hipMemsetAsync(cur, 0, NN * sizeof(int), stream);
    edge_fill_k<<<EB, 256, 0, stream>>>(src, dst, rowp, cur, esrc, EE);
    // layer 1: xwb = featb @ W1 (bf16 out)
    gemm_mfma_k<<<MG, 256, 0, stream>>>(featb, nullptr, nullptr, br[b].W1t, nullptr,
                                        nullptr, xwb, NN, 1, 0);
    gcn_gather_k<<<GATH_N, 256, 0, stream>>>(xwb, rowp, esrc, dis, br[b].b1, x1b, NN);
    // layer 2
    gemm_mfma_k<<<MG, 256, 0, stream>>>(x1b, nullptr, nullptr, br[b].W2t, nullptr,
                                        nullptr, xwb, NN, 1, 0);
    gcn_gather_k<<<GATH_N, 256, 0, stream>>>(xwb, rowp, esrc, dis, br[b].b2, x2b, NN);
    // fc: concat @ Wfc + bfc, relu -> fp32 xw
    gemm_mfma_k<<<MG, 256, 0, stream>>>(featb, x1b, x2b, br[b].Wfct, br[b].bfc,
                                        xw, nullptr, NN, 3, 2);
    // batchnorm -> bf16
    (void)hipMemsetAsync(sums, 0, 2 * 128 * sizeof(float), stream);
    bn_stats_k<<<STAT_N, 256, 0, stream>>>(xw, sums, sumsq, NN);
    bn_finalize_k<<<1, 128, 0, stream>>>(sums, sumsq, br[b].g, br[b].be, scl, sht);
    bn_apply_k<<<APPLY_N, 256, 0, stream>>>(xw, scl, sht, br[b].bnb, (int)(NF / 4));
  }

  // heads (K=256, fp32 out)
  const int MGC = (NCELL + 127) / 128;
  const int MGD = (NDRUG + 127) / 128;
  gemm_mfma_k<<<MGC, 256, 0, stream>>>(bnSb, bnRb, nullptr, Wcellt, b_cell,
                                       out, nullptr, NCELL, 2, 2);
  float* outD = out + (size_t)NCELL * 128;
  gemm_mfma_k<<<MGD, 256, 0, stream>>>(bnSb + (size_t)NCELL * 128, bnRb + (size_t)NCELL * 128,
                                       nullptr, Wdrugt, b_drug, outD, nullptr, NDRUG, 2, 2);
}

// Round 6
// 1177.380 us; speedup vs baseline: 1.7331x; 1.1118x over previous
//
#include <hip/hip_runtime.h>

#define NN 100000
#define NCELL 40000
#define NDRUG 60000
#define EE 1600000
#define FEPS 1e-5f
#define SLOPE 0.2f
#define NB 391  // (NN+255)/256

typedef unsigned short ushort_t;
typedef unsigned int uint_t;
typedef __attribute__((ext_vector_type(8))) __bf16 bf16x8;
typedef __attribute__((ext_vector_type(4))) float f32x4;

__device__ __forceinline__ ushort_t f2bf(float x) {
  uint_t u = __float_as_uint(x);
  u = (u + 0x7FFFu + ((u >> 16) & 1u)) >> 16;  // RNE
  return (ushort_t)u;
}
__device__ __forceinline__ uint_t pack2bf(float a, float b) {
  return (uint_t)f2bf(a) | ((uint_t)f2bf(b) << 16);
}
__device__ __forceinline__ float bf2f(ushort_t x) {
  return __uint_as_float(((uint_t)x) << 16);
}

// ---------------------------------------------------------------- converts
__global__ __launch_bounds__(256) void feat_cvt_k(const float* __restrict__ X,
                                                  ushort_t* __restrict__ Y, int n8) {
  int i = blockIdx.x * 256 + threadIdx.x;
  if (i >= n8) return;
  const float4* in4 = (const float4*)X;
  float4 a = in4[2 * i], b = in4[2 * i + 1];
  uint4 o;
  o.x = pack2bf(a.x, a.y); o.y = pack2bf(a.z, a.w);
  o.z = pack2bf(b.x, b.y); o.w = pack2bf(b.z, b.w);
  ((uint4*)Y)[i] = o;
}

struct WC { const float* s; ushort_t* d; int K; };
struct WCA { WC w[6]; };
// Wt[col][k] = bf16(W[k][col]); grid (6, maxK/16), block 128 (one col per thread)
__global__ __launch_bounds__(128) void wcvt_k(WCA a) {
  const WC wc = a.w[blockIdx.x];
  const int k0 = blockIdx.y * 16;
  if (k0 >= wc.K) return;
  const int col = threadIdx.x;
  const int k1 = min(k0 + 16, wc.K);
  for (int k = k0; k < k1; k++)
    wc.d[(size_t)col * wc.K + k] = f2bf(wc.s[(size_t)k * 128 + col]);
}

// ---------------------------------------------------------------- CSR build
__global__ __launch_bounds__(256) void edge_count_k(const int* __restrict__ dst,
                                                    int* __restrict__ deg, int E) {
  int e = blockIdx.x * 256 + threadIdx.x;
  if (e < E) atomicAdd(&deg[dst[e]], 1);
}

__global__ __launch_bounds__(256) void scan_partial_k(const int* __restrict__ deg,
                                                      int* __restrict__ part, int n) {
  __shared__ int sm[256];
  const int t = threadIdx.x;
  const int i = blockIdx.x * 256 + t;
  sm[t] = (i < n) ? deg[i] : 0;
  __syncthreads();
  for (int off = 128; off > 0; off >>= 1) {
    if (t < off) sm[t] += sm[t + off];
    __syncthreads();
  }
  if (t == 0) part[blockIdx.x] = sm[0];
}

__global__ __launch_bounds__(512) void scan_top_k(int* __restrict__ part, int nb,
                                                  int* __restrict__ rowp, int n, int E) {
  __shared__ int sm[512];
  const int t = threadIdx.x;
  int v = (t < nb) ? part[t] : 0;
  sm[t] = v;
  __syncthreads();
  for (int off = 1; off < 512; off <<= 1) {
    int u = (t >= off) ? sm[t - off] : 0;
    __syncthreads();
    sm[t] += u;
    __syncthreads();
  }
  if (t < nb) part[t] = (t == 0) ? 0 : sm[t - 1];
  if (t == 0) rowp[n] = E;
}

__global__ __launch_bounds__(256) void scan_final_k(const int* __restrict__ deg,
                                                    const int* __restrict__ part,
                                                    int* __restrict__ rowp,
                                                    float* __restrict__ dis, int n) {
  __shared__ int sm[256];
  const int t = threadIdx.x;
  const int i = blockIdx.x * 256 + t;
  const int d = (i < n) ? deg[i] : 0;
  sm[t] = d;
  __syncthreads();
  for (int off = 1; off < 256; off <<= 1) {
    int u = (t >= off) ? sm[t - off] : 0;
    __syncthreads();
    sm[t] += u;
    __syncthreads();
  }
  if (i < n) {
    rowp[i] = part[blockIdx.x] + sm[t] - d;
    dis[i] = (d > 0) ? rsqrtf((float)d) : 0.f;
  }
}

__global__ __launch_bounds__(256) void edge_fill_k(const int* __restrict__ src,
                                                   const int* __restrict__ dst,
                                                   const int* __restrict__ rowp,
                                                   int* __restrict__ cur,
                                                   int* __restrict__ esrc, int E) {
  int e = blockIdx.x * 256 + threadIdx.x;
  if (e >= E) return;
  int d = dst[e];
  int p = atomicAdd(&cur[d], 1);
  esrc[rowp[d] + p] = src[e];
}

// ---------------------------------------------------------------- MFMA GEMM
// Y[nrows,128] = act( [X0|X1|X2](bf16)[nrows, nseg*128] @ W[nseg*128,128] + bias )
// Wt is bf16 [128 cols][Ktot=nseg*128] (transposed). Output: Yf (fp32) or Yb (bf16).
// act: 0 none, 1 leaky, 2 relu. Block: 4 waves x 32 rows = 128 rows.
__global__ __launch_bounds__(256) void gemm_mfma_k(const ushort_t* __restrict__ X0,
                                                   const ushort_t* __restrict__ X1,
                                                   const ushort_t* __restrict__ X2,
                                                   const ushort_t* __restrict__ Wt,
                                                   const float* __restrict__ bias,
                                                   float* __restrict__ Yf,
                                                   ushort_t* __restrict__ Yb,
                                                   int nrows, int nseg, int act) {
  const int t = threadIdx.x;
  const int wave = t >> 6;
  const int lane = t & 63;
  const int lane15 = lane & 15;
  const int lgrp = lane >> 4;  // 0..3
  const int row0w = blockIdx.x * 128 + wave * 32;  // wave owns 32 rows
  const int Ktot = nseg * 128;

  // clamped A rows for the two 16-row subtiles
  const int r0c = min(row0w + lane15, nrows - 1);
  const int r1c = min(row0w + 16 + lane15, nrows - 1);

  f32x4 acc[2][8];
#pragma unroll
  for (int m = 0; m < 2; m++)
#pragma unroll
    for (int f = 0; f < 8; f++) acc[m][f] = (f32x4)0.f;

  const ushort_t* Xs[3] = {X0, X1, X2};
  for (int seg = 0; seg < nseg; seg++) {
    const ushort_t* Xp = Xs[seg];
    const ushort_t* Wp = Wt + seg * 128;
#pragma unroll
    for (int kk = 0; kk < 128; kk += 32) {
      const int ko = kk + lgrp * 8;
      bf16x8 a0 = *(const bf16x8*)(Xp + (size_t)r0c * 128 + ko);
      bf16x8 a1 = *(const bf16x8*)(Xp + (size_t)r1c * 128 + ko);
#pragma unroll
      for (int f = 0; f < 8; f++) {
        bf16x8 bb = *(const bf16x8*)(Wp + (size_t)(f * 16 + lane15) * Ktot + ko);
        acc[0][f] = __builtin_amdgcn_mfma_f32_16x16x32_bf16(a0, bb, acc[0][f], 0, 0, 0);
        acc[1][f] = __builtin_amdgcn_mfma_f32_16x16x32_bf16(a1, bb, acc[1][f], 0, 0, 0);
      }
    }
  }

#pragma unroll
  for (int m = 0; m < 2; m++) {
    const int rbase = row0w + m * 16 + lgrp * 4;
#pragma unroll
    for (int f = 0; f < 8; f++) {
      const int col = f * 16 + lane15;
      const float bv = bias ? bias[col] : 0.f;
#pragma unroll
      for (int j = 0; j < 4; j++) {
        const int r = rbase + j;
        if (r < nrows) {
          float o = acc[m][f][j] + bv;
          if (act == 1) o = o > 0.f ? o : SLOPE * o;
          else if (act == 2) o = o > 0.f ? o : 0.f;
          if (Yf) Yf[(size_t)r * 128 + col] = o;
          else Yb[(size_t)r * 128 + col] = f2bf(o);
        }
      }
    }
  }
}

// ---------------------------------------------------------------- gather (bf16)
// Wave per dst row; 4 slots x 16 lanes. Slot e handles edges start+e, +4, ...
// Lane (slot, ch) reads 8 channels (uint4) of the slot's src row.
// out[r,:] = bf16( leaky_relu( sum dis[src]*dis[r]*xw[src,:] + bias ) )
__global__ __launch_bounds__(256) void gcn_gather_k(const ushort_t* __restrict__ xw,
                                                    const int* __restrict__ rowp,
                                                    const int* __restrict__ esrc,
                                                    const float* __restrict__ dis,
                                                    const float* __restrict__ bias,
                                                    ushort_t* __restrict__ out, int nrows) {
  const int lane = threadIdx.x & 63;
  const int row = (blockIdx.x * blockDim.x + threadIdx.x) >> 6;
  if (row >= nrows) return;
  const int slot = lane >> 4;
  const int ch = lane & 15;        // channels ch*8 .. ch*8+7
  const int start = rowp[row];
  const int end = rowp[row + 1];
  const float dr = dis[row];

  float a0 = 0.f, a1 = 0.f, a2 = 0.f, a3 = 0.f, a4 = 0.f, a5 = 0.f, a6 = 0.f, a7 = 0.f;
#pragma unroll 2
  for (int j = start + slot; j < end; j += 4) {
    const int s = esrc[j];
    const float w = dis[s] * dr;
    const uint4 v = *(const uint4*)(xw + (size_t)s * 128 + ch * 8);
    a0 += w * __uint_as_float(v.x << 16);
    a1 += w * __uint_as_float(v.x & 0xFFFF0000u);
    a2 += w * __uint_as_float(v.y << 16);
    a3 += w * __uint_as_float(v.y & 0xFFFF0000u);
    a4 += w * __uint_as_float(v.z << 16);
    a5 += w * __uint_as_float(v.z & 0xFFFF0000u);
    a6 += w * __uint_as_float(v.w << 16);
    a7 += w * __uint_as_float(v.w & 0xFFFF0000u);
  }
  // reduce across the 4 slots (lane bits 4 and 5)
  a0 += __shfl_xor(a0, 16, 64); a1 += __shfl_xor(a1, 16, 64);
  a2 += __shfl_xor(a2, 16, 64); a3 += __shfl_xor(a3, 16, 64);
  a4 += __shfl_xor(a4, 16, 64); a5 += __shfl_xor(a5, 16, 64);
  a6 += __shfl_xor(a6, 16, 64); a7 += __shfl_xor(a7, 16, 64);
  a0 += __shfl_xor(a0, 32, 64); a1 += __shfl_xor(a1, 32, 64);
  a2 += __shfl_xor(a2, 32, 64); a3 += __shfl_xor(a3, 32, 64);
  a4 += __shfl_xor(a4, 32, 64); a5 += __shfl_xor(a5, 32, 64);
  a6 += __shfl_xor(a6, 32, 64); a7 += __shfl_xor(a7, 32, 64);

  if (slot == 0) {
    const float4 b0 = *(const float4*)(bias + ch * 8);
    const float4 b1 = *(const float4*)(bias + ch * 8 + 4);
    float o0 = a0 + b0.x, o1 = a1 + b0.y, o2 = a2 + b0.z, o3 = a3 + b0.w;
    float o4 = a4 + b1.x, o5 = a5 + b1.y, o6 = a6 + b1.z, o7 = a7 + b1.w;
    o0 = o0 > 0.f ? o0 : SLOPE * o0; o1 = o1 > 0.f ? o1 : SLOPE * o1;
    o2 = o2 > 0.f ? o2 : SLOPE * o2; o3 = o3 > 0.f ? o3 : SLOPE * o3;
    o4 = o4 > 0.f ? o4 : SLOPE * o4; o5 = o5 > 0.f ? o5 : SLOPE * o5;
    o6 = o6 > 0.f ? o6 : SLOPE * o6; o7 = o7 > 0.f ? o7 : SLOPE * o7;
    uint4 o;
    o.x = pack2bf(o0, o1); o.y = pack2bf(o2, o3);
    o.z = pack2bf(o4, o5); o.w = pack2bf(o6, o7);
    *(uint4*)(out + (size_t)row * 128 + ch * 8) = o;
  }
}

// ---------------------------------------------------------------- batchnorm
// stats over bf16 input (what the heads consume)
__global__ __launch_bounds__(256) void bn_stats_k(const ushort_t* __restrict__ X,
                                                  float* __restrict__ sums,
                                                  float* __restrict__ sumsq, int nrows) {
  __shared__ float ls[256], lq[256];
  const int t = threadIdx.x;
  const int c = t & 127;
  const int h = t >> 7;
  const int r0 = blockIdx.x * 256;
  const int r1 = min(r0 + 256, nrows);
  float s = 0.f, q = 0.f;
  for (int r = r0 + h; r < r1; r += 2) {
    float v = bf2f(X[(size_t)r * 128 + c]);
    s += v;
    q += v * v;
  }
  ls[t] = s;
  lq[t] = q;
  __syncthreads();
  if (t < 128) {
    s = ls[t] + ls[t + 128];
    q = lq[t] + lq[t + 128];
    atomicAdd(&sums[c], s);
    atomicAdd(&sumsq[c], q);
  }
}

__global__ void bn_finalize_k(const float* __restrict__ sums,
                              const float* __restrict__ sumsq,
                              const float* __restrict__ g,
                              const float* __restrict__ be,
                              float* __restrict__ scl, float* __restrict__ sht) {
  int c = threadIdx.x;
  float mu = sums[c] * (1.f / (float)NN);
  float var = sumsq[c] * (1.f / (float)NN) - mu * mu;
  float s = g[c] * rsqrtf(var + FEPS);
  scl[c] = s;
  sht[c] = be[c] - mu * s;
}

// fold BN affine into head weight: Wf[col][k] = bf16(scl_cat[k]*W[k][col]),
// bf[col] = b[col] + sum_k sht_cat[k]*W[k][col]. One block, 128 threads.
__global__ __launch_bounds__(128) void fold_head_k(const float* __restrict__ W,
                                                   const float* __restrict__ b,
                                                   const float* __restrict__ sclS,
                                                   const float* __restrict__ shtS,
                                                   const float* __restrict__ sclR,
                                                   const float* __restrict__ shtR,
                                                   ushort_t* __restrict__ Wf,
                                                   float* __restrict__ bf) {
  const int col = threadIdx.x;
  float acc = b[col];
  for (int k = 0; k < 256; k++) {
    const float w = W[(size_t)k * 128 + col];
    const float sc = (k < 128) ? sclS[k] : sclR[k - 128];
    const float sh = (k < 128) ? shtS[k] : shtR[k - 128];
    acc += sh * w;
    Wf[(size_t)col * 256 + k] = f2bf(sc * w);
  }
  bf[col] = acc;
}

// ---------------------------------------------------------------- launch
extern "C" void kernel_launch(void* const* d_in, const int* in_sizes, int n_in,
                              void* d_out, int out_size, void* d_ws, size_t ws_size,
                              hipStream_t stream) {
  const float* feature = (const float*)d_in[0];
  const int* sen_edge = (const int*)d_in[1];
  const int* res_edge = (const int*)d_in[2];
  const float* W_sen1 = (const float*)d_in[3];
  const float* b_sen1 = (const float*)d_in[4];
  const float* W_sen2 = (const float*)d_in[5];
  const float* b_sen2 = (const float*)d_in[6];
  const float* W_senfc = (const float*)d_in[7];
  const float* b_senfc = (const float*)d_in[8];
  const float* g_sen = (const float*)d_in[9];
  const float* be_sen = (const float*)d_in[10];
  const float* W_res1 = (const float*)d_in[11];
  const float* b_res1 = (const float*)d_in[12];
  const float* W_res2 = (const float*)d_in[13];
  const float* b_res2 = (const float*)d_in[14];
  const float* W_resfc = (const float*)d_in[15];
  const float* b_resfc = (const float*)d_in[16];
  const float* g_res = (const float*)d_in[17];
  const float* be_res = (const float*)d_in[18];
  const float* W_cell = (const float*)d_in[19];
  const float* b_cell = (const float*)d_in[20];
  const float* W_drug = (const float*)d_in[21];
  const float* b_drug = (const float*)d_in[22];
  float* out = (float*)d_out;

  const size_t NF = (size_t)NN * 128;
  char* wsb = (char*)d_ws;
  ushort_t* featb = (ushort_t*)wsb;                 // NF bf16 each
  ushort_t* x1b = featb + NF;
  ushort_t* x2b = x1b + NF;
  ushort_t* xwb = x2b + NF;
  ushort_t* xallSb = xwb + NF;
  ushort_t* xallRb = xallSb + NF;
  ushort_t* wt = xallRb + NF;                       // weight pool
  ushort_t* W1tS = wt;                              // 128*128
  ushort_t* W2tS = W1tS + 128 * 128;
  ushort_t* WfctS = W2tS + 128 * 128;               // 128*384
  ushort_t* W1tR = WfctS + 128 * 384;
  ushort_t* W2tR = W1tR + 128 * 128;
  ushort_t* WfctR = W2tR + 128 * 128;
  ushort_t* Wcellf = WfctR + 128 * 384;             // 128*256 (folded)
  ushort_t* Wdrugf = Wcellf + 128 * 256;
  float* dis = (float*)(Wdrugf + 128 * 256);        // NN
  int* rowp = (int*)(dis + NN);                     // NN+1
  int* cur = rowp + (NN + 1);                       // NN
  int* esrc = cur + NN;                             // EE
  float* sums = (float*)(esrc + EE);                // 128
  float* sumsq = sums + 128;
  float* sclS = sumsq + 128;
  float* shtS = sclS + 128;
  float* sclR = shtS + 128;
  float* shtR = sclR + 128;
  float* bcellf = shtR + 128;
  float* bdrugf = bcellf + 128;
  int* part = (int*)(bdrugf + 128);                 // NB

  const int MG = (NN + 127) / 128;          // 782
  const int GATH_N = (NN * 64 + 255) / 256; // 25000
  const int EB = (EE + 255) / 256;          // 6250
  const int STAT_N = (NN + 255) / 256;      // 391

  // one-time converts
  feat_cvt_k<<<(int)(NF / 8 + 255) / 256, 256, 0, stream>>>(feature, featb, (int)(NF / 8));
  WCA wa;
  wa.w[0] = {W_sen1, W1tS, 128};  wa.w[1] = {W_sen2, W2tS, 128};
  wa.w[2] = {W_senfc, WfctS, 384}; wa.w[3] = {W_res1, W1tR, 128};
  wa.w[4] = {W_res2, W2tR, 128};  wa.w[5] = {W_resfc, WfctR, 384};
  wcvt_k<<<dim3(6, 24), 128, 0, stream>>>(wa);

  struct Branch {
    const int* edge;
    ushort_t* W1t; const float* b1;
    ushort_t* W2t; const float* b2;
    ushort_t* Wfct; const float* bfc;
    const float* g; const float* be;
    ushort_t* xallb; float* scl; float* sht;
  };
  Branch br[2] = {
      {sen_edge, W1tS, b_sen1, W2tS, b_sen2, WfctS, b_senfc, g_sen, be_sen, xallSb, sclS, shtS},
      {res_edge, W1tR, b_res1, W2tR, b_res2, WfctR, b_resfc, g_res, be_res, xallRb, sclR, shtR},
  };

  for (int b = 0; b < 2; b++) {
    const int* src = br[b].edge;
    const int* dst = br[b].edge + EE;
    (void)hipMemsetAsync(cur, 0, NN * sizeof(int), stream);
    edge_count_k<<<EB, 256, 0, stream>>>(dst, cur, EE);
    scan_partial_k<<<NB, 256, 0, stream>>>(cur, part, NN);
    scan_top_k<<<1, 512, 0, stream>>>(part, NB, rowp, NN, EE);
    scan_final_k<<<NB, 256, 0, stream>>>(cur, part, rowp, dis, NN);
    (void)hipMemsetAsync(cur, 0, NN * sizeof(int), stream);
    edge_fill_k<<<EB, 256, 0, stream>>>(src, dst, rowp, cur, esrc, EE);
    // layer 1: xwb = featb @ W1 (bf16 out)
    gemm_mfma_k<<<MG, 256, 0, stream>>>(featb, nullptr, nullptr, br[b].W1t, nullptr,
                                        nullptr, xwb, NN, 1, 0);
    gcn_gather_k<<<GATH_N, 256, 0, stream>>>(xwb, rowp, esrc, dis, br[b].b1, x1b, NN);
    // layer 2
    gemm_mfma_k<<<MG, 256, 0, stream>>>(x1b, nullptr, nullptr, br[b].W2t, nullptr,
                                        nullptr, xwb, NN, 1, 0);
    gcn_gather_k<<<GATH_N, 256, 0, stream>>>(xwb, rowp, esrc, dis, br[b].b2, x2b, NN);
    // fc: relu(concat @ Wfc + bfc) -> bf16 xall
    gemm_mfma_k<<<MG, 256, 0, stream>>>(featb, x1b, x2b, br[b].Wfct, br[b].bfc,
                                        nullptr, br[b].xallb, NN, 3, 2);
    // batchnorm stats (over bf16) -> scl/sht
    (void)hipMemsetAsync(sums, 0, 2 * 128 * sizeof(float), stream);
    bn_stats_k<<<STAT_N, 256, 0, stream>>>(br[b].xallb, sums, sumsq, NN);
    bn_finalize_k<<<1, 128, 0, stream>>>(sums, sumsq, br[b].g, br[b].be, br[b].scl, br[b].sht);
  }

  // fold BN into head weights, then heads (K=256, fp32 out)
  fold_head_k<<<1, 128, 0, stream>>>(W_cell, b_cell, sclS, shtS, sclR, shtR, Wcellf, bcellf);
  fold_head_k<<<1, 128, 0, stream>>>(W_drug, b_drug, sclS, shtS, sclR, shtR, Wdrugf, bdrugf);
  const int MGC = (NCELL + 127) / 128;
  const int MGD = (NDRUG + 127) / 128;
  gemm_mfma_k<<<MGC, 256, 0, stream>>>(xallSb, xallRb, nullptr, Wcellf, bcellf,
                                       out, nullptr, NCELL, 2, 2);
  float* outD = out + (size_t)NCELL * 128;
  gemm_mfma_k<<<MGD, 256, 0, stream>>>(xallSb + (size_t)NCELL * 128, xallRb + (size_t)NCELL * 128,
                                       nullptr, Wdrugf, bdrugf, outD, nullptr, NDRUG, 2, 2);
}